// Round 5
// baseline (877.448 us; speedup 1.0000x reference)
//
#include <hip/hip_runtime.h>
#include <hip/hip_bf16.h>

#define N_ROWS 8192
#define DIM 512
#define C_CLSN 1000
#define LOW_THRE (1.0f / 1000.0f)
#define LDK 40   // padded LDS leading dim (bf16 elems) to break bank conflicts

typedef __bf16 bf16x8 __attribute__((ext_vector_type(8)));
typedef float floatx4 __attribute__((ext_vector_type(4)));
typedef unsigned long long ull;
typedef ull ull2 __attribute__((ext_vector_type(2)));

// ---------------- KZ: detect conf_mask storage (int32 / uint8 / int64) -------
__global__ __launch_bounds__(256) void kz_detect_v5(const int* __restrict__ conf,
                                                    int* __restrict__ flag) {
  __shared__ int sbad, sodd1, seven1;
  int tid = threadIdx.x;
  if (tid == 0) { sbad = 0; sodd1 = 0; seven1 = 0; }
  __syncthreads();
  for (int i = tid; i < 2048; i += 256) {   // 8 KB window: in-range for all layouts
    int v = conf[i];
    if (v != 0 && v != 1) atomicOr(&sbad, 1);
    if (v == 1) { if (i & 1) atomicAdd(&sodd1, 1); else atomicAdd(&seven1, 1); }
  }
  __syncthreads();
  if (tid == 0) {
    int mode = 0;                                // int32 0/1
    if (sbad) mode = 1;                          // packed uint8 bools
    else if (seven1 > 0 && sodd1 == 0) mode = 2; // int64 0/1
    flag[0] = mode;
  }
}

__device__ __forceinline__ bool read_conf(const int* conf, int mode, int r) {
  if (mode == 1) return ((const unsigned char*)conf)[r] != 0;
  if (mode == 2) return ((const long long*)conf)[r] != 0;
  return conf[r] != 0;
}

// ---------------- KP: stable partition rows by conf (conf first) -------------
// perm[newpos] = origrow; counters[3] = nconf. Deterministic.
__global__ __launch_bounds__(1024) void kp_perm_v5(const int* __restrict__ conf,
                                                   const int* __restrict__ cmode,
                                                   int* __restrict__ perm,
                                                   int* __restrict__ counters) {
  int tid = threadIdx.x;
  __shared__ int sc[1024];
  int mode = cmode[0];
  int r0 = tid * 8;
  int f[8]; int cnt = 0;
  #pragma unroll
  for (int k = 0; k < 8; ++k) { f[k] = read_conf(conf, mode, r0 + k) ? 1 : 0; cnt += f[k]; }
  sc[tid] = cnt;
  __syncthreads();
  for (int off = 1; off < 1024; off <<= 1) {    // Hillis-Steele inclusive scan
    int v = (tid >= off) ? sc[tid - off] : 0;
    __syncthreads();
    sc[tid] += v;
    __syncthreads();
  }
  int incl = sc[tid];
  int excl = incl - cnt;
  int total = sc[1023];
  if (tid == 0) counters[3] = total;
  int cpos = excl;
  int npos = total + (r0 - excl);
  #pragma unroll
  for (int k = 0; k < 8; ++k) {
    if (f[k]) perm[cpos++] = r0 + k;
    else      perm[npos++] = r0 + k;
  }
}

// ---------------- KA: L2-normalize feature rows -> bf16 (permuted order) -----
__global__ __launch_bounds__(64) void ka_featnorm_v5(const float* __restrict__ feature,
                                                     const int* __restrict__ perm,
                                                     __bf16* __restrict__ featBF) {
  int p = blockIdx.x;
  int orig = perm[p];
  int l = threadIdx.x;
  const float* fr = feature + (size_t)orig * DIM;
  int c0 = l * 8;
  float4 v0 = *(const float4*)(fr + c0);
  float4 v1 = *(const float4*)(fr + c0 + 4);
  float ss = v0.x*v0.x + v0.y*v0.y + v0.z*v0.z + v0.w*v0.w
           + v1.x*v1.x + v1.y*v1.y + v1.z*v1.z + v1.w*v1.w;
  #pragma unroll
  for (int m = 1; m < 64; m <<= 1) ss += __shfl_xor(ss, m);
  float sc = 1.0f / fmaxf(sqrtf(ss), 1e-12f);
  bf16x8 bv;
  bv[0] = (__bf16)(v0.x * sc); bv[1] = (__bf16)(v0.y * sc);
  bv[2] = (__bf16)(v0.z * sc); bv[3] = (__bf16)(v0.w * sc);
  bv[4] = (__bf16)(v1.x * sc); bv[5] = (__bf16)(v1.y * sc);
  bv[6] = (__bf16)(v1.z * sc); bv[7] = (__bf16)(v1.w * sc);
  *(bf16x8*)(featBF + (size_t)p * DIM + c0) = bv;
}

// ---------------- KB: proj[c][d] = sum_k raw[c][k] * cP[d][k] ----------------
__global__ __launch_bounds__(256) void kb_proj_v5(const float* __restrict__ raw,
                                                  const float* __restrict__ cP,
                                                  float* __restrict__ proj) {
  int tid = threadIdx.x;
  int c0 = blockIdx.x * 8;
  __shared__ float sraw[8 * DIM];  // 16 KB
  for (int idx = tid; idx < 8 * DIM; idx += 256)
    sraw[idx] = raw[(size_t)c0 * DIM + idx];
  __syncthreads();
  int d0 = tid, d1 = tid + 256;
  float acc0[8], acc1[8];
  #pragma unroll
  for (int cc = 0; cc < 8; ++cc) { acc0[cc] = 0.f; acc1[cc] = 0.f; }
  for (int k = 0; k < DIM; k += 4) {
    float4 w0 = *(const float4*)&cP[(size_t)d0 * DIM + k];
    float4 w1 = *(const float4*)&cP[(size_t)d1 * DIM + k];
    #pragma unroll
    for (int cc = 0; cc < 8; ++cc) {
      const float* sr = &sraw[cc * DIM + k];
      acc0[cc] += sr[0]*w0.x + sr[1]*w0.y + sr[2]*w0.z + sr[3]*w0.w;
      acc1[cc] += sr[0]*w1.x + sr[1]*w1.y + sr[2]*w1.z + sr[3]*w1.w;
    }
  }
  #pragma unroll
  for (int cc = 0; cc < 8; ++cc) {
    proj[(size_t)(c0 + cc) * DIM + d0] = acc0[cc];
    proj[(size_t)(c0 + cc) * DIM + d1] = acc1[cc];
  }
}

// ---------------- KC: row-normalize proxy in place ---------------------------
__global__ __launch_bounds__(64) void kc_norm_v5(float* __restrict__ proxy) {
  int r = blockIdx.x, l = threadIdx.x;
  float* pr = proxy + (size_t)r * DIM;
  int c0 = l * 8;
  float4 v0 = *(float4*)(pr + c0);
  float4 v1 = *(float4*)(pr + c0 + 4);
  float ss = v0.x*v0.x + v0.y*v0.y + v0.z*v0.z + v0.w*v0.w
           + v1.x*v1.x + v1.y*v1.y + v1.z*v1.z + v1.w*v1.w;
  #pragma unroll
  for (int m = 1; m < 64; m <<= 1) ss += __shfl_xor(ss, m);
  float sc = 1.0f / fmaxf(sqrtf(ss), 1e-12f);
  v0.x *= sc; v0.y *= sc; v0.z *= sc; v0.w *= sc;
  v1.x *= sc; v1.y *= sc; v1.z *= sc; v1.w *= sc;
  *(float4*)(pr + c0)     = v0;
  *(float4*)(pr + c0 + 4) = v1;
}

// ---------------- KD: per-row prob processing (permuted index p) -------------
__global__ __launch_bounds__(256) void kd_prob_v5(const float* __restrict__ prob,
                                                  const int* __restrict__ perm,
                                                  const int* __restrict__ counters_ro,
                                                  const float* __restrict__ proxy,
                                                  const __bf16* __restrict__ featBF,
                                                  ull* __restrict__ bits,
                                                  int* __restrict__ top1a,
                                                  float* __restrict__ pos,
                                                  int* __restrict__ counters) {
  int p = blockIdx.x;
  int orig = perm[p];
  bool is_conf = p < counters_ro[3];           // partitioned: conf rows first
  int tid = threadIdx.x;
  __shared__ ull sbits[16];
  __shared__ int scnt;
  __shared__ int scand[1024];
  __shared__ float swt[1024];
  __shared__ float redv[256];
  __shared__ int redi[256];
  if (tid < 16) sbits[tid] = 0ULL;
  if (tid == 0) scnt = 0;
  __syncthreads();
  const float* pr = prob + (size_t)orig * C_CLSN;
  float bv = -1e30f; int bidx = 0x7fffffff;
  for (int c = tid; c < C_CLSN; c += 256) {
    float pv = pr[c];
    if (pv > bv) { bv = pv; bidx = c; }
    if (!is_conf && pv > LOW_THRE) {
      int k = atomicAdd(&scnt, 1);
      scand[k] = c; swt[k] = pv;
      atomicOr(&sbits[c >> 6], 1ULL << (c & 63));
    }
  }
  redv[tid] = bv; redi[tid] = bidx;
  __syncthreads();
  for (int s = 128; s > 0; s >>= 1) {
    if (tid < s) {
      float v2 = redv[tid + s]; int i2 = redi[tid + s];
      if (v2 > redv[tid] || (v2 == redv[tid] && i2 < redi[tid])) { redv[tid] = v2; redi[tid] = i2; }
    }
    __syncthreads();
  }
  int top1 = redi[0];
  if (tid == 0) {
    top1a[p] = top1;
    if (is_conf) {
      sbits[top1 >> 6] = 1ULL << (top1 & 63);  // one-hot pred_class
    } else {
      atomicAdd(&counters[0], scnt);  // sc_count
      atomicAdd(&counters[1], 1);     // denom
    }
  }
  __syncthreads();
  if (tid < 16) bits[(size_t)p * 16 + tid] = sbits[tid];
  float a0 = 0.f, a1 = 0.f;
  int d0 = tid, d1 = tid + 256;
  if (is_conf) {
    const float* pq = proxy + (size_t)top1 * DIM;
    a0 = pq[d0]; a1 = pq[d1];
  } else {
    int n = scnt;
    for (int e = 0; e < n; ++e) {
      int c = scand[e]; float w = swt[e];
      const float* pq = proxy + (size_t)c * DIM;
      a0 += w * pq[d0]; a1 += w * pq[d1];
    }
  }
  const __bf16* fr = featBF + (size_t)p * DIM;
  float dot = a0 * (float)fr[d0] + a1 * (float)fr[d1];
  __syncthreads();
  redv[tid] = dot;
  __syncthreads();
  for (int s = 128; s > 0; s >>= 1) {
    if (tid < s) redv[tid] += redv[tid + s];
    __syncthreads();
  }
  if (tid == 0) pos[p] = fminf(fmaxf(redv[0], -1.1f), 1.1f);  // |pos|<=1 math bound
}

// ---------------- KE: fused sim GEMM + tile-specialized mask + sum(exp) ------
// Rows conf-partitioned: tiles classified -> cheap top1-compare / bit-probe
// paths; full 1000-bit AND only when neither side is all-conf (~27% of tiles).
__global__ __launch_bounds__(256, 3) void ke_sim_v5(const __bf16* __restrict__ featBF,
                                                    const ull* __restrict__ bits,
                                                    const int* __restrict__ top1a,
                                                    const int* __restrict__ counters_ro,
                                                    float* __restrict__ S) {
  __shared__ __align__(16) __bf16 As[128 * LDK];   // 10240 B
  __shared__ __align__(16) __bf16 Bs[128 * LDK];   // 10240 B
  __shared__ ull bsI[16 * 128];                    // 16384 B  [word][row]
  __shared__ ull bsJ[16 * 128];                    // 16384 B  [word][col]
  __shared__ int t1I[128], t1J[128];               // 1024 B
  // total 54272 B -> 3 blocks/CU (162816 <= 163840)

  int bi = blockIdx.x >> 6;
  int bj = blockIdx.x & 63;
  int nconf = counters_ro[3];
  bool allcI = (bi * 128 + 128) <= nconf;
  bool allcJ = (bj * 128 + 128) <= nconf;
  int mode = (allcI && allcJ) ? 0 : (allcI ? 1 : (allcJ ? 2 : 3));

  int tid = threadIdx.x;
  int wv = tid >> 6, lane = tid & 63;
  int wi = wv >> 1, wj = wv & 1;
  int lr = lane >> 4, lc = lane & 15;

  // stage top1 (cheap, always) + bitsets (only the side(s) the mask path reads)
  if (tid < 128)      t1I[tid]       = top1a[bi * 128 + tid];
  else                t1J[tid - 128] = top1a[bj * 128 + tid - 128];
  if (mode == 1 || mode == 3) {
    #pragma unroll
    for (int e = 0; e < 8; ++e) {
      int flat = tid + e * 256;
      int row = flat & 127, w = flat >> 7;   // conflict-free LDS write pattern
      bsJ[w * 128 + row] = bits[(size_t)(bj * 128 + row) * 16 + w];
    }
  }
  if (mode == 2 || mode == 3) {
    #pragma unroll
    for (int e = 0; e < 8; ++e) {
      int flat = tid + e * 256;
      int row = flat & 127, w = flat >> 7;
      bsI[w * 128 + row] = bits[(size_t)(bi * 128 + row) * 16 + w];
    }
  }

  floatx4 acc[4][4];
  floatx4 zero = {0.f, 0.f, 0.f, 0.f};
  #pragma unroll
  for (int ti = 0; ti < 4; ++ti)
    #pragma unroll
    for (int tj = 0; tj < 4; ++tj) acc[ti][tj] = zero;

  const __bf16* Abase = featBF + (size_t)bi * 128 * DIM;
  const __bf16* Bbase = featBF + (size_t)bj * 128 * DIM;

  for (int kt = 0; kt < DIM; kt += 32) {
    __syncthreads();
    #pragma unroll
    for (int t = 0; t < 2; ++t) {
      int idx = tid + t * 256;
      int rw = idx >> 2, cc = (idx & 3) * 8;
      *(bf16x8*)&As[rw * LDK + cc] = *(const bf16x8*)&Abase[(size_t)rw * DIM + kt + cc];
      *(bf16x8*)&Bs[rw * LDK + cc] = *(const bf16x8*)&Bbase[(size_t)rw * DIM + kt + cc];
    }
    __syncthreads();
    bf16x8 afr[4], bfr[4];
    #pragma unroll
    for (int ti = 0; ti < 4; ++ti)
      afr[ti] = *(bf16x8*)&As[(wi * 64 + ti * 16 + lc) * LDK + lr * 8];
    #pragma unroll
    for (int tj = 0; tj < 4; ++tj)
      bfr[tj] = *(bf16x8*)&Bs[(wj * 64 + tj * 16 + lc) * LDK + lr * 8];
    #pragma unroll
    for (int ti = 0; ti < 4; ++ti)
      #pragma unroll
      for (int tj = 0; tj < 4; ++tj)
        acc[ti][tj] = __builtin_amdgcn_mfma_f32_16x16x32_bf16(afr[ti], bfr[tj], acc[ti][tj], 0, 0, 0);
  }
  __syncthreads();   // bs/t1 writes (pre-K-loop) -> visible; K-loop LDS reads done

  int tJv[4];
  #pragma unroll
  for (int tj = 0; tj < 4; ++tj) tJv[tj] = t1J[wj * 64 + tj * 16 + lc];

  #pragma unroll
  for (int ti = 0; ti < 4; ++ti) {
    int ibase = wi * 64 + ti * 16 + lr * 4;   // C/D: row=(lane>>4)*4+reg, col=lane&15
    unsigned inter[16];
    if (mode == 0) {            // conf x conf: intersect <=> same top1
      #pragma unroll
      for (int rr = 0; rr < 4; ++rr) {
        int tI = t1I[ibase + rr];
        #pragma unroll
        for (int tj = 0; tj < 4; ++tj) inter[rr * 4 + tj] = (tI == tJv[tj]);
      }
    } else if (mode == 1) {     // conf-I: probe J's bitset with top1_i
      #pragma unroll
      for (int rr = 0; rr < 4; ++rr) {
        int tI = t1I[ibase + rr];
        int w = tI >> 6, b = tI & 63;
        #pragma unroll
        for (int tj = 0; tj < 4; ++tj) {
          ull word = bsJ[w * 128 + wj * 64 + tj * 16 + lc];
          inter[rr * 4 + tj] = (unsigned)((word >> b) & 1ULL);
        }
      }
    } else if (mode == 2) {     // conf-J: probe I's bitset with top1_j
      #pragma unroll
      for (int tj = 0; tj < 4; ++tj) {
        int tJ = tJv[tj];
        int w = tJ >> 6, b = tJ & 63;
        #pragma unroll
        for (int rr = 0; rr < 4; ++rr) {
          ull word = bsI[w * 128 + ibase + rr];
          inter[rr * 4 + tj] = (unsigned)((word >> b) & 1ULL);
        }
      }
    } else {                    // general: full 1000-bit AND (correct for all rows)
      #pragma unroll
      for (int q = 0; q < 16; ++q) inter[q] = 0u;
      #pragma unroll
      for (int w = 0; w < 16; ++w) {
        ull2 a01 = *(const ull2*)&bsI[w * 128 + ibase];
        ull2 a23 = *(const ull2*)&bsI[w * 128 + ibase + 2];
        ull aw[4] = {a01[0], a01[1], a23[0], a23[1]};
        ull bw[4];
        #pragma unroll
        for (int tj = 0; tj < 4; ++tj) bw[tj] = bsJ[w * 128 + wj * 64 + tj * 16 + lc];
        #pragma unroll
        for (int rr = 0; rr < 4; ++rr)
          #pragma unroll
          for (int tj = 0; tj < 4; ++tj) {
            ull t = aw[rr] & bw[tj];
            inter[rr * 4 + tj] |= (unsigned)(t | (t >> 32));
          }
      }
    }
    float rs[4] = {0.f, 0.f, 0.f, 0.f};
    #pragma unroll
    for (int rr = 0; rr < 4; ++rr)
      #pragma unroll
      for (int tj = 0; tj < 4; ++tj) {
        float sim = acc[ti][tj][rr];
        sim = fminf(sim, 1.0f);   // unit rows: math no-op; bounds bf16 edge
        float e_ = ((inter[rr * 4 + tj] == 0u) && (sim >= 1e-6f)) ? __expf(sim) : 0.f;
        rs[rr] += e_;
      }
    #pragma unroll
    for (int m = 1; m < 16; m <<= 1)
      #pragma unroll
      for (int rr = 0; rr < 4; ++rr) rs[rr] += __shfl_xor(rs[rr], m);
    if (lc == 0) {
      #pragma unroll
      for (int rr = 0; rr < 4; ++rr)
        atomicAdd(&S[(size_t)bi * 128 + ibase + rr], rs[rr]);
    }
  }
}

// ---------------- KF: final reduction — fp32 out -----------------------------
__global__ __launch_bounds__(1024) void kf_final_v5(const float* __restrict__ pos,
                                                    const float* __restrict__ S,
                                                    const int* __restrict__ counters,
                                                    float* __restrict__ out) {
  __shared__ float red[1024];
  int tid = threadIdx.x;
  float local = 0.f;
  for (int i = tid; i < N_ROWS; i += 1024) {
    float p = pos[i];
    float s = fmaxf(S[i], 0.0f);
    local += logf(expf(p) + s) - p;   // -logp[:,0]
  }
  red[tid] = local;
  __syncthreads();
  for (int s = 512; s > 0; s >>= 1) {
    if (tid < s) red[tid] += red[tid + s];
    __syncthreads();
  }
  if (tid == 0) {
    float loss = red[0] / (float)N_ROWS;
    int scc = counters[0], dn = counters[1];
    float scn = (dn > 0) ? ((float)scc / (float)(dn > 1 ? dn : 1)) : 0.f;
    out[0] = loss;
    out[1] = scn;
  }
}

extern "C" void kernel_launch(void* const* d_in, const int* in_sizes, int n_in,
                              void* d_out, int out_size, void* d_ws, size_t ws_size,
                              hipStream_t stream) {
  const float* feature   = (const float*)d_in[0];
  const float* proxy_raw = (const float*)d_in[1];
  const float* cP        = (const float*)d_in[2];
  const float* prob      = (const float*)d_in[3];
  const int*   conf      = (const int*)d_in[4];
  float* out = (float*)d_out;

  size_t need = (size_t)N_ROWS * DIM * 2      // featBF   8 MB
              + (size_t)C_CLSN * DIM * 4      // proxy    2 MB
              + (size_t)N_ROWS * 16 * 8       // bits     1 MB
              + (size_t)N_ROWS * 4            // pos
              + (size_t)N_ROWS * 4            // S
              + 256                           // counters
              + (size_t)N_ROWS * 4            // perm
              + (size_t)N_ROWS * 4;           // top1a
  if (ws_size < need) return;                 // out stays 0 -> err 8.0625 signature

  char* ws = (char*)d_ws;
  __bf16* featBF = (__bf16*)ws;  ws += (size_t)N_ROWS * DIM * 2;
  float* proxy   = (float*)ws;   ws += (size_t)C_CLSN * DIM * 4;
  ull* bits      = (ull*)ws;     ws += (size_t)N_ROWS * 16 * 8;
  float* pos     = (float*)ws;   ws += (size_t)N_ROWS * 4;
  float* S       = (float*)ws;   ws += (size_t)N_ROWS * 4;
  int* counters  = (int*)ws;     ws += 256;   // [0]=sc_count [1]=denom [2]=cmode [3]=nconf
  int* perm      = (int*)ws;     ws += (size_t)N_ROWS * 4;
  int* top1a     = (int*)ws;     ws += (size_t)N_ROWS * 4;

  hipMemsetAsync(S, 0, (size_t)N_ROWS * 4 + 256, stream);  // S + counters contiguous
  kz_detect_v5<<<1, 256, 0, stream>>>(conf, &counters[2]);
  kp_perm_v5<<<1, 1024, 0, stream>>>(conf, &counters[2], perm, counters);
  ka_featnorm_v5<<<N_ROWS, 64, 0, stream>>>(feature, perm, featBF);
  kb_proj_v5<<<C_CLSN / 8, 256, 0, stream>>>(proxy_raw, cP, proxy);
  kc_norm_v5<<<C_CLSN, 64, 0, stream>>>(proxy);
  kd_prob_v5<<<N_ROWS, 256, 0, stream>>>(prob, perm, counters, proxy, featBF,
                                         bits, top1a, pos, counters);
  ke_sim_v5<<<64 * 64, 256, 0, stream>>>(featBF, bits, top1a, counters, S);
  kf_final_v5<<<1, 1024, 0, stream>>>(pos, S, counters, out);
}

// Round 6
// 454.746 us; speedup vs baseline: 1.9295x; 1.9295x over previous
//
#include <hip/hip_runtime.h>
#include <hip/hip_bf16.h>

#define N_ROWS 8192
#define DIM 512
#define C_CLSN 1000
#define LOW_THRE (1.0f / 1000.0f)
#define LDK 40   // padded LDS leading dim (bf16 elems) to break bank conflicts

typedef __bf16 bf16x8 __attribute__((ext_vector_type(8)));
typedef float floatx4 __attribute__((ext_vector_type(4)));
typedef unsigned long long ull;
typedef ull ull2 __attribute__((ext_vector_type(2)));

// ---------------- KZ: detect conf_mask storage (int32 / uint8 / int64) -------
__global__ __launch_bounds__(256) void kz_detect_v6(const int* __restrict__ conf,
                                                    int* __restrict__ flag) {
  __shared__ int sbad, sodd1, seven1;
  int tid = threadIdx.x;
  if (tid == 0) { sbad = 0; sodd1 = 0; seven1 = 0; }
  __syncthreads();
  for (int i = tid; i < 2048; i += 256) {
    int v = conf[i];
    if (v != 0 && v != 1) atomicOr(&sbad, 1);
    if (v == 1) { if (i & 1) atomicAdd(&sodd1, 1); else atomicAdd(&seven1, 1); }
  }
  __syncthreads();
  if (tid == 0) {
    int mode = 0;                                // int32 0/1
    if (sbad) mode = 1;                          // packed uint8 bools
    else if (seven1 > 0 && sodd1 == 0) mode = 2; // int64 0/1
    flag[0] = mode;
  }
}

__device__ __forceinline__ bool read_conf(const int* conf, int mode, int r) {
  if (mode == 1) return ((const unsigned char*)conf)[r] != 0;
  if (mode == 2) return ((const long long*)conf)[r] != 0;
  return conf[r] != 0;
}

// ---------------- KP: stable partition rows by conf (conf first) -------------
__global__ __launch_bounds__(1024) void kp_perm_v6(const int* __restrict__ conf,
                                                   const int* __restrict__ cmode,
                                                   int* __restrict__ perm,
                                                   int* __restrict__ counters) {
  int tid = threadIdx.x;
  __shared__ int sc[1024];
  int mode = cmode[0];
  int r0 = tid * 8;
  int f[8]; int cnt = 0;
  #pragma unroll
  for (int k = 0; k < 8; ++k) { f[k] = read_conf(conf, mode, r0 + k) ? 1 : 0; cnt += f[k]; }
  sc[tid] = cnt;
  __syncthreads();
  for (int off = 1; off < 1024; off <<= 1) {
    int v = (tid >= off) ? sc[tid - off] : 0;
    __syncthreads();
    sc[tid] += v;
    __syncthreads();
  }
  int incl = sc[tid];
  int excl = incl - cnt;
  int total = sc[1023];
  if (tid == 0) counters[3] = total;
  int cpos = excl;
  int npos = total + (r0 - excl);
  #pragma unroll
  for (int k = 0; k < 8; ++k) {
    if (f[k]) perm[cpos++] = r0 + k;
    else      perm[npos++] = r0 + k;
  }
}

// ---------------- KA: L2-normalize feature rows -> bf16 (permuted order) -----
__global__ __launch_bounds__(64) void ka_featnorm_v6(const float* __restrict__ feature,
                                                     const int* __restrict__ perm,
                                                     __bf16* __restrict__ featBF) {
  int p = blockIdx.x;
  int orig = perm[p];
  int l = threadIdx.x;
  const float* fr = feature + (size_t)orig * DIM;
  int c0 = l * 8;
  float4 v0 = *(const float4*)(fr + c0);
  float4 v1 = *(const float4*)(fr + c0 + 4);
  float ss = v0.x*v0.x + v0.y*v0.y + v0.z*v0.z + v0.w*v0.w
           + v1.x*v1.x + v1.y*v1.y + v1.z*v1.z + v1.w*v1.w;
  #pragma unroll
  for (int m = 1; m < 64; m <<= 1) ss += __shfl_xor(ss, m);
  float sc = 1.0f / fmaxf(sqrtf(ss), 1e-12f);
  bf16x8 bv;
  bv[0] = (__bf16)(v0.x * sc); bv[1] = (__bf16)(v0.y * sc);
  bv[2] = (__bf16)(v0.z * sc); bv[3] = (__bf16)(v0.w * sc);
  bv[4] = (__bf16)(v1.x * sc); bv[5] = (__bf16)(v1.y * sc);
  bv[6] = (__bf16)(v1.z * sc); bv[7] = (__bf16)(v1.w * sc);
  *(bf16x8*)(featBF + (size_t)p * DIM + c0) = bv;
}

// ---------------- KB: proj[c][d] = sum_k raw[c][k] * cP[d][k] ----------------
__global__ __launch_bounds__(256) void kb_proj_v6(const float* __restrict__ raw,
                                                  const float* __restrict__ cP,
                                                  float* __restrict__ proj) {
  int tid = threadIdx.x;
  int c0 = blockIdx.x * 8;
  __shared__ float sraw[8 * DIM];  // 16 KB
  for (int idx = tid; idx < 8 * DIM; idx += 256)
    sraw[idx] = raw[(size_t)c0 * DIM + idx];
  __syncthreads();
  int d0 = tid, d1 = tid + 256;
  float acc0[8], acc1[8];
  #pragma unroll
  for (int cc = 0; cc < 8; ++cc) { acc0[cc] = 0.f; acc1[cc] = 0.f; }
  for (int k = 0; k < DIM; k += 4) {
    float4 w0 = *(const float4*)&cP[(size_t)d0 * DIM + k];
    float4 w1 = *(const float4*)&cP[(size_t)d1 * DIM + k];
    #pragma unroll
    for (int cc = 0; cc < 8; ++cc) {
      const float* sr = &sraw[cc * DIM + k];
      acc0[cc] += sr[0]*w0.x + sr[1]*w0.y + sr[2]*w0.z + sr[3]*w0.w;
      acc1[cc] += sr[0]*w1.x + sr[1]*w1.y + sr[2]*w1.z + sr[3]*w1.w;
    }
  }
  #pragma unroll
  for (int cc = 0; cc < 8; ++cc) {
    proj[(size_t)(c0 + cc) * DIM + d0] = acc0[cc];
    proj[(size_t)(c0 + cc) * DIM + d1] = acc1[cc];
  }
}

// ---------------- KC: row-normalize proxy in place ---------------------------
__global__ __launch_bounds__(64) void kc_norm_v6(float* __restrict__ proxy) {
  int r = blockIdx.x, l = threadIdx.x;
  float* pr = proxy + (size_t)r * DIM;
  int c0 = l * 8;
  float4 v0 = *(float4*)(pr + c0);
  float4 v1 = *(float4*)(pr + c0 + 4);
  float ss = v0.x*v0.x + v0.y*v0.y + v0.z*v0.z + v0.w*v0.w
           + v1.x*v1.x + v1.y*v1.y + v1.z*v1.z + v1.w*v1.w;
  #pragma unroll
  for (int m = 1; m < 64; m <<= 1) ss += __shfl_xor(ss, m);
  float sc = 1.0f / fmaxf(sqrtf(ss), 1e-12f);
  v0.x *= sc; v0.y *= sc; v0.z *= sc; v0.w *= sc;
  v1.x *= sc; v1.y *= sc; v1.z *= sc; v1.w *= sc;
  *(float4*)(pr + c0)     = v0;
  *(float4*)(pr + c0 + 4) = v1;
}

// ---------------- KD: per-row prob processing (permuted index p) -------------
__global__ __launch_bounds__(256) void kd_prob_v6(const float* __restrict__ prob,
                                                  const int* __restrict__ perm,
                                                  const int* __restrict__ counters_ro,
                                                  const float* __restrict__ proxy,
                                                  const __bf16* __restrict__ featBF,
                                                  ull* __restrict__ bits,
                                                  int* __restrict__ top1a,
                                                  float* __restrict__ pos,
                                                  int* __restrict__ counters) {
  int p = blockIdx.x;
  int orig = perm[p];
  bool is_conf = p < counters_ro[3];           // partitioned: conf rows first
  int tid = threadIdx.x;
  __shared__ ull sbits[16];
  __shared__ int scnt;
  __shared__ int scand[1024];
  __shared__ float swt[1024];
  __shared__ float redv[256];
  __shared__ int redi[256];
  if (tid < 16) sbits[tid] = 0ULL;
  if (tid == 0) scnt = 0;
  __syncthreads();
  const float* pr = prob + (size_t)orig * C_CLSN;
  float bv = -1e30f; int bidx = 0x7fffffff;
  for (int c = tid; c < C_CLSN; c += 256) {
    float pv = pr[c];
    if (pv > bv) { bv = pv; bidx = c; }
    if (!is_conf && pv > LOW_THRE) {
      int k = atomicAdd(&scnt, 1);
      scand[k] = c; swt[k] = pv;
      atomicOr(&sbits[c >> 6], 1ULL << (c & 63));
    }
  }
  redv[tid] = bv; redi[tid] = bidx;
  __syncthreads();
  for (int s = 128; s > 0; s >>= 1) {
    if (tid < s) {
      float v2 = redv[tid + s]; int i2 = redi[tid + s];
      if (v2 > redv[tid] || (v2 == redv[tid] && i2 < redi[tid])) { redv[tid] = v2; redi[tid] = i2; }
    }
    __syncthreads();
  }
  int top1 = redi[0];
  if (tid == 0) {
    top1a[p] = top1;
    if (is_conf) {
      sbits[top1 >> 6] = 1ULL << (top1 & 63);
    } else {
      atomicAdd(&counters[0], scnt);  // sc_count
      atomicAdd(&counters[1], 1);     // denom
    }
  }
  __syncthreads();
  if (tid < 16) bits[(size_t)p * 16 + tid] = sbits[tid];
  float a0 = 0.f, a1 = 0.f;
  int d0 = tid, d1 = tid + 256;
  if (is_conf) {
    const float* pq = proxy + (size_t)top1 * DIM;
    a0 = pq[d0]; a1 = pq[d1];
  } else {
    int n = scnt;
    for (int e = 0; e < n; ++e) {
      int c = scand[e]; float w = swt[e];
      const float* pq = proxy + (size_t)c * DIM;
      a0 += w * pq[d0]; a1 += w * pq[d1];
    }
  }
  const __bf16* fr = featBF + (size_t)p * DIM;
  float dot = a0 * (float)fr[d0] + a1 * (float)fr[d1];
  __syncthreads();
  redv[tid] = dot;
  __syncthreads();
  for (int s = 128; s > 0; s >>= 1) {
    if (tid < s) redv[tid] += redv[tid + s];
    __syncthreads();
  }
  if (tid == 0) pos[p] = fminf(fmaxf(redv[0], -1.1f), 1.1f);  // |pos|<=1 math bound
}

// ---------------- KE: fused sim GEMM + tile-specialized mask + sum(exp) ------
// Upper-triangular 128x128 tiles (2080 blocks); mirror column sums for bi!=bj.
// NOTE: no min-occupancy clamp — VGPR must hold acc[4][4] (spill = 750 MB HBM, r5).
__global__ __launch_bounds__(256) void ke_sim_v6(const __bf16* __restrict__ featBF,
                                                 const ull* __restrict__ bits,
                                                 const int* __restrict__ top1a,
                                                 const int* __restrict__ counters_ro,
                                                 float* __restrict__ S) {
  __shared__ __align__(16) __bf16 As[128 * LDK];   // 10240 B
  __shared__ __align__(16) __bf16 Bs[128 * LDK];   // 10240 B
  __shared__ ull bsI[16 * 128];                    // 16384 B  [word][row]
  __shared__ ull bsJ[16 * 128];                    // 16384 B  [word][col]
  __shared__ int t1I[128], t1J[128];               // 1024 B

  // upper-tri decode: b -> (bi, bj), bi <= bj
  int b = blockIdx.x;
  int bi = 0, rem = b;
  while (rem >= 64 - bi) { rem -= 64 - bi; bi++; }
  int bj = bi + rem;

  int nconf = counters_ro[3];
  bool allcI = (bi * 128 + 128) <= nconf;
  bool allcJ = (bj * 128 + 128) <= nconf;
  // bi <= bj + conf-first partition => allcJ implies allcI
  int mode = allcJ ? 0 : (allcI ? 1 : 3);

  int tid = threadIdx.x;
  int wv = tid >> 6, lane = tid & 63;
  int wi = wv >> 1, wj = wv & 1;
  int lr = lane >> 4, lc = lane & 15;

  if (tid < 128)      t1I[tid]       = top1a[bi * 128 + tid];
  else                t1J[tid - 128] = top1a[bj * 128 + tid - 128];
  if (mode != 0) {        // need J's bitset (probe or full)
    #pragma unroll
    for (int e = 0; e < 8; ++e) {
      int flat = tid + e * 256;
      int row = flat & 127, w = flat >> 7;   // 2-way LDS write alias (free)
      bsJ[w * 128 + row] = bits[(size_t)(bj * 128 + row) * 16 + w];
    }
  }
  if (mode == 3) {        // need I's bitset too
    #pragma unroll
    for (int e = 0; e < 8; ++e) {
      int flat = tid + e * 256;
      int row = flat & 127, w = flat >> 7;
      bsI[w * 128 + row] = bits[(size_t)(bi * 128 + row) * 16 + w];
    }
  }

  floatx4 acc[4][4];
  floatx4 zero = {0.f, 0.f, 0.f, 0.f};
  #pragma unroll
  for (int ti = 0; ti < 4; ++ti)
    #pragma unroll
    for (int tj = 0; tj < 4; ++tj) acc[ti][tj] = zero;

  const __bf16* Abase = featBF + (size_t)bi * 128 * DIM;
  const __bf16* Bbase = featBF + (size_t)bj * 128 * DIM;

  for (int kt = 0; kt < DIM; kt += 32) {
    __syncthreads();
    #pragma unroll
    for (int t = 0; t < 2; ++t) {
      int idx = tid + t * 256;
      int rw = idx >> 2, cc = (idx & 3) * 8;
      *(bf16x8*)&As[rw * LDK + cc] = *(const bf16x8*)&Abase[(size_t)rw * DIM + kt + cc];
      *(bf16x8*)&Bs[rw * LDK + cc] = *(const bf16x8*)&Bbase[(size_t)rw * DIM + kt + cc];
    }
    __syncthreads();
    bf16x8 afr[4], bfr[4];
    #pragma unroll
    for (int ti = 0; ti < 4; ++ti)
      afr[ti] = *(bf16x8*)&As[(wi * 64 + ti * 16 + lc) * LDK + lr * 8];
    #pragma unroll
    for (int tj = 0; tj < 4; ++tj)
      bfr[tj] = *(bf16x8*)&Bs[(wj * 64 + tj * 16 + lc) * LDK + lr * 8];
    #pragma unroll
    for (int ti = 0; ti < 4; ++ti)
      #pragma unroll
      for (int tj = 0; tj < 4; ++tj)
        acc[ti][tj] = __builtin_amdgcn_mfma_f32_16x16x32_bf16(afr[ti], bfr[tj], acc[ti][tj], 0, 0, 0);
  }
  __syncthreads();   // K-loop LDS reads done; bs/t1 (pre-loop) visible

  int tJv[4];
  #pragma unroll
  for (int tj = 0; tj < 4; ++tj) tJv[tj] = t1J[wj * 64 + tj * 16 + lc];

  float cs[4] = {0.f, 0.f, 0.f, 0.f};   // mirror column sums (bi != bj)
  #pragma unroll
  for (int ti = 0; ti < 4; ++ti) {
    int ibase = wi * 64 + ti * 16 + lr * 4;   // C/D: row=(lane>>4)*4+reg, col=lane&15
    unsigned inter[16];
    if (mode == 0) {            // conf x conf: intersect <=> same top1
      #pragma unroll
      for (int rr = 0; rr < 4; ++rr) {
        int tI = t1I[ibase + rr];
        #pragma unroll
        for (int tj = 0; tj < 4; ++tj) inter[rr * 4 + tj] = (tI == tJv[tj]);
      }
    } else if (mode == 1) {     // conf-I: probe J's bitset with top1_i
      #pragma unroll
      for (int rr = 0; rr < 4; ++rr) {
        int tI = t1I[ibase + rr];
        int w = tI >> 6, bb = tI & 63;
        #pragma unroll
        for (int tj = 0; tj < 4; ++tj) {
          ull word = bsJ[w * 128 + wj * 64 + tj * 16 + lc];
          inter[rr * 4 + tj] = (unsigned)((word >> bb) & 1ULL);
        }
      }
    } else {                    // general: full 1000-bit AND
      #pragma unroll
      for (int q = 0; q < 16; ++q) inter[q] = 0u;
      #pragma unroll
      for (int w = 0; w < 16; ++w) {
        ull2 a01 = *(const ull2*)&bsI[w * 128 + ibase];
        ull2 a23 = *(const ull2*)&bsI[w * 128 + ibase + 2];
        ull aw[4] = {a01[0], a01[1], a23[0], a23[1]};
        ull bw[4];
        #pragma unroll
        for (int tj = 0; tj < 4; ++tj) bw[tj] = bsJ[w * 128 + wj * 64 + tj * 16 + lc];
        #pragma unroll
        for (int rr = 0; rr < 4; ++rr)
          #pragma unroll
          for (int tj = 0; tj < 4; ++tj) {
            ull t = aw[rr] & bw[tj];
            inter[rr * 4 + tj] |= (unsigned)(t | (t >> 32));
          }
      }
    }
    float rs[4] = {0.f, 0.f, 0.f, 0.f};
    #pragma unroll
    for (int rr = 0; rr < 4; ++rr)
      #pragma unroll
      for (int tj = 0; tj < 4; ++tj) {
        float sim = acc[ti][tj][rr];
        sim = fminf(sim, 1.0f);   // unit rows: math no-op
        float e_ = ((inter[rr * 4 + tj] == 0u) && (sim >= 1e-6f)) ? __expf(sim) : 0.f;
        rs[rr] += e_;
        cs[tj] += e_;
      }
    #pragma unroll
    for (int m = 1; m < 16; m <<= 1)
      #pragma unroll
      for (int rr = 0; rr < 4; ++rr) rs[rr] += __shfl_xor(rs[rr], m);
    if (lc == 0) {
      #pragma unroll
      for (int rr = 0; rr < 4; ++rr)
        atomicAdd(&S[(size_t)bi * 128 + ibase + rr], rs[rr]);
    }
  }
  if (bi != bj) {   // mirror: (j,i) has identical value by symmetry -> column sums
    #pragma unroll
    for (int tj = 0; tj < 4; ++tj) {
      cs[tj] += __shfl_xor(cs[tj], 16);   // reduce over lr (lane bits 4,5)
      cs[tj] += __shfl_xor(cs[tj], 32);
    }
    if (lr == 0) {
      #pragma unroll
      for (int tj = 0; tj < 4; ++tj)
        atomicAdd(&S[(size_t)bj * 128 + wj * 64 + tj * 16 + lc], cs[tj]);
    }
  }
}

// ---------------- KF: final reduction — fp32 out -----------------------------
__global__ __launch_bounds__(1024) void kf_final_v6(const float* __restrict__ pos,
                                                    const float* __restrict__ S,
                                                    const int* __restrict__ counters,
                                                    float* __restrict__ out) {
  __shared__ float red[1024];
  int tid = threadIdx.x;
  float local = 0.f;
  for (int i = tid; i < N_ROWS; i += 1024) {
    float p = pos[i];
    float s = fmaxf(S[i], 0.0f);
    local += logf(expf(p) + s) - p;   // -logp[:,0]
  }
  red[tid] = local;
  __syncthreads();
  for (int s = 512; s > 0; s >>= 1) {
    if (tid < s) red[tid] += red[tid + s];
    __syncthreads();
  }
  if (tid == 0) {
    float loss = red[0] / (float)N_ROWS;
    int scc = counters[0], dn = counters[1];
    float scn = (dn > 0) ? ((float)scc / (float)(dn > 1 ? dn : 1)) : 0.f;
    out[0] = loss;
    out[1] = scn;
  }
}

extern "C" void kernel_launch(void* const* d_in, const int* in_sizes, int n_in,
                              void* d_out, int out_size, void* d_ws, size_t ws_size,
                              hipStream_t stream) {
  const float* feature   = (const float*)d_in[0];
  const float* proxy_raw = (const float*)d_in[1];
  const float* cP        = (const float*)d_in[2];
  const float* prob      = (const float*)d_in[3];
  const int*   conf      = (const int*)d_in[4];
  float* out = (float*)d_out;

  size_t need = (size_t)N_ROWS * DIM * 2      // featBF   8 MB
              + (size_t)C_CLSN * DIM * 4      // proxy    2 MB
              + (size_t)N_ROWS * 16 * 8       // bits     1 MB
              + (size_t)N_ROWS * 4            // pos
              + (size_t)N_ROWS * 4            // S
              + 256                           // counters
              + (size_t)N_ROWS * 4            // perm
              + (size_t)N_ROWS * 4;           // top1a
  if (ws_size < need) return;

  char* ws = (char*)d_ws;
  __bf16* featBF = (__bf16*)ws;  ws += (size_t)N_ROWS * DIM * 2;
  float* proxy   = (float*)ws;   ws += (size_t)C_CLSN * DIM * 4;
  ull* bits      = (ull*)ws;     ws += (size_t)N_ROWS * 16 * 8;
  float* pos     = (float*)ws;   ws += (size_t)N_ROWS * 4;
  float* S       = (float*)ws;   ws += (size_t)N_ROWS * 4;
  int* counters  = (int*)ws;     ws += 256;   // [0]=sc_count [1]=denom [2]=cmode [3]=nconf
  int* perm      = (int*)ws;     ws += (size_t)N_ROWS * 4;
  int* top1a     = (int*)ws;     ws += (size_t)N_ROWS * 4;

  hipMemsetAsync(S, 0, (size_t)N_ROWS * 4 + 256, stream);  // S + counters contiguous
  kz_detect_v6<<<1, 256, 0, stream>>>(conf, &counters[2]);
  kp_perm_v6<<<1, 1024, 0, stream>>>(conf, &counters[2], perm, counters);
  ka_featnorm_v6<<<N_ROWS, 64, 0, stream>>>(feature, perm, featBF);
  kb_proj_v6<<<C_CLSN / 8, 256, 0, stream>>>(proxy_raw, cP, proxy);
  kc_norm_v6<<<C_CLSN, 64, 0, stream>>>(proxy);
  kd_prob_v6<<<N_ROWS, 256, 0, stream>>>(prob, perm, counters, proxy, featBF,
                                         bits, top1a, pos, counters);
  ke_sim_v6<<<2080, 256, 0, stream>>>(featBF, bits, top1a, counters, S);
  kf_final_v6<<<1, 1024, 0, stream>>>(pos, S, counters, out);
}